// Round 2
// baseline (1109.778 us; speedup 1.0000x reference)
//
#include <hip/hip_runtime.h>
#include <hip/hip_bf16.h>
#include <math.h>

#define B_ 8
#define N_ 512
#define K_ 128
#define M_ 100
#define NPAIR (B_*N_)    // 4096
#define DRLEN 1600
#define F0 240

static __device__ __forceinline__ float tanh_f(float x){
  float xc = fminf(fmaxf(x, -15.f), 15.f);
  float e = __expf(2.f*xc);
  return __fdividef(e - 1.f, e + 1.f);
}

// ---------------------------------------------------------------------------
// Kernel A: per (b,n) pair — cutoff, Ri, embedding MLP, einsums -> DR[1600]
// 128 threads, thread t = neighbor j.
// ---------------------------------------------------------------------------
__global__ __launch_bounds__(128) void embed_kernel(
    const float* __restrict__ img,
    const float* __restrict__ ew0, const float* __restrict__ eb0,
    const float* __restrict__ ew1, const float* __restrict__ eb1,
    const float* __restrict__ ew2, const float* __restrict__ eb2,
    float* __restrict__ DR)
{
  __shared__ float sG[K_][M_];     // 51200 B
  __shared__ float sRi[K_][4];     // 2048 B
  __shared__ float sA[16*4];
  __shared__ float sB[4*M_];

  const int pair = blockIdx.x;
  const int t = threadIdx.x;       // j

  // ---- phase 1: S, Ri ----
  const float* p = img + ((size_t)pair*K_ + t)*4;
  float4 v = *(const float4*)p;
  float x = v.x, y = v.y, z = v.z, fl = v.w;
  float R = fmaf(x, x, fmaf(y, y, z*z));
  bool mask = fl > 0.f;
  bool lt10 = R < 10.f;
  float safe = (R == 0.f) ? 1.f : R;
  float Sc = 0.5f*cosf(0.20943951023931953f*(R - 10.f)) + 0.5f;  // pi/15
  float S;
  if (mask && lt10)            S = 1.f/safe;
  else if (!lt10 && R < 25.f)  S = Sc;
  else                         S = 0.f;
  float coef = mask ? S/safe : 0.f;
  sRi[t][0] = S; sRi[t][1] = coef*x; sRi[t][2] = coef*y; sRi[t][3] = coef*z;

  // ---- phase 2: embedding MLP (per-thread, registers) ----
  float h0[25];
  #pragma unroll
  for (int c = 0; c < 25; c++)
    h0[c] = tanh_f(fmaf(S, ew0[c], eb0[c]));

  float h1[50];
  #pragma unroll
  for (int c = 0; c < 50; c += 2){
    float a0 = eb1[c], a1 = eb1[c+1];
    #pragma unroll
    for (int k = 0; k < 25; k++){
      float h = h0[k];
      a0 = fmaf(h, ew1[k*50 + c],     a0);
      a1 = fmaf(h, ew1[k*50 + c + 1], a1);
    }
    h1[c]   = tanh_f(a0);
    h1[c+1] = tanh_f(a1);
  }

  for (int c = 0; c < M_; c += 2){
    float a0 = eb2[c], a1 = eb2[c+1];
    float b0 = 0.f, b1v = 0.f;
    #pragma unroll
    for (int k = 0; k < 50; k += 2){
      float ha = h1[k], hb = h1[k+1];
      a0  = fmaf(ha, ew2[k*M_ + c],         a0);
      a1  = fmaf(ha, ew2[k*M_ + c + 1],     a1);
      b0  = fmaf(hb, ew2[(k+1)*M_ + c],     b0);
      b1v = fmaf(hb, ew2[(k+1)*M_ + c + 1], b1v);
    }
    sG[t][c]   = tanh_f(a0 + b0);
    sG[t][c+1] = tanh_f(a1 + b1v);
  }
  __syncthreads();

  // ---- phase 3: tmpA[16][4] = sum_j G16[j][m] * Ri[j][f] ----
  if (t < 64){
    int m = t & 15, f = t >> 4;
    float a = 0.f;
    #pragma unroll 4
    for (int j = 0; j < K_; j++) a = fmaf(sG[j][m], sRi[j][f], a);
    sA[m*4 + f] = a;
  }
  // tmpB[4][100] = sum_j Ri[j][f] * G[j][m]
  for (int o = t; o < 4*M_; o += 128){
    int f = o / M_, m = o % M_;
    float a = 0.f;
    #pragma unroll 4
    for (int j = 0; j < K_; j++) a = fmaf(sRi[j][f], sG[j][m], a);
    sB[o] = a;
  }
  __syncthreads();

  // ---- phase 4: DR[m][h] = sum_f tmpA[m][f]*tmpB[f][h] ----
  float* drp = DR + (size_t)pair*DRLEN;
  for (int o = t; o < DRLEN; o += 128){
    int m = o / M_, h = o % M_;
    float d = sA[m*4+0]*sB[0*M_+h] + sA[m*4+1]*sB[1*M_+h]
            + sA[m*4+2]*sB[2*M_+h] + sA[m*4+3]*sB[3*M_+h];
    drp[o] = d;
  }
}

// ---------------------------------------------------------------------------
// GEMM: Y[M,N] = act(X[M,K] @ W[K,N] + bias), all f32.
// 64x64 tile, 256 threads, 4x4 per thread. K % 16 == 0, M % 64 == 0.
// ---------------------------------------------------------------------------
template<int TANH>
__global__ __launch_bounds__(256) void gemm_k(
    const float* __restrict__ X, const float* __restrict__ W,
    const float* __restrict__ bias, float* __restrict__ Y,
    int M, int N, int K)
{
  __shared__ float Xs[16][68];   // [k][row]
  __shared__ float Ws[16][68];   // [k][col]
  const int tid = threadIdx.x;
  const int tx = tid & 15, ty = tid >> 4;
  const int row0 = blockIdx.x * 64;
  const int col0 = blockIdx.y * 64;
  const int lk = tid & 15, lr = tid >> 4;   // X loader
  const int ln = tid & 63, lw = tid >> 6;   // W loader
  float acc[4][4] = {};

  for (int kt = 0; kt < K; kt += 16){
    #pragma unroll
    for (int i = 0; i < 4; i++){
      int r = lr + i*16;
      Xs[lk][r] = X[(size_t)(row0 + r)*K + kt + lk];
    }
    #pragma unroll
    for (int i = 0; i < 4; i++){
      int kk = lw + i*4;
      int c = col0 + ln;
      Ws[kk][ln] = (c < N) ? W[(size_t)(kt + kk)*N + c] : 0.f;
    }
    __syncthreads();
    #pragma unroll
    for (int kk = 0; kk < 16; kk++){
      float a[4], b[4];
      #pragma unroll
      for (int i = 0; i < 4; i++) a[i] = Xs[kk][ty*4 + i];
      #pragma unroll
      for (int i = 0; i < 4; i++) b[i] = Ws[kk][tx*4 + i];
      #pragma unroll
      for (int i = 0; i < 4; i++)
        #pragma unroll
        for (int jj = 0; jj < 4; jj++)
          acc[i][jj] = fmaf(a[i], b[jj], acc[i][jj]);
    }
    __syncthreads();
  }

  #pragma unroll
  for (int i = 0; i < 4; i++){
    int r = row0 + ty*4 + i;
    #pragma unroll
    for (int jj = 0; jj < 4; jj++){
      int c = col0 + tx*4 + jj;
      if (c < N){
        float v = acc[i][jj] + bias[c];
        if (TANH) v = tanh_f(v);
        Y[(size_t)r*N + c] = v;
      }
    }
  }
}

// ---------------------------------------------------------------------------
// GEMV: Ei[m] = H[m,:240] . w3 + b3 ; one wave per row.
// ---------------------------------------------------------------------------
__global__ __launch_bounds__(256) void gemv_out(
    const float* __restrict__ H, const float* __restrict__ w3,
    const float* __restrict__ b3, float* __restrict__ Ei,
    float* __restrict__ outEi)
{
  int row  = (blockIdx.x * 256 + threadIdx.x) >> 6;
  int lane = threadIdx.x & 63;
  const float* hp = H + (size_t)row * F0;
  float a = 0.f;
  for (int k = lane; k < F0; k += 64) a = fmaf(hp[k], w3[k], a);
  #pragma unroll
  for (int off = 32; off; off >>= 1) a += __shfl_down(a, off, 64);
  if (lane == 0){
    float e = a + b3[0];
    Ei[row] = e;
    outEi[row] = e;
  }
}

// ---------------------------------------------------------------------------
// Etot[b] = sum_n Ei[b,n]
// ---------------------------------------------------------------------------
__global__ __launch_bounds__(256) void etot_k(
    const float* __restrict__ Ei, float* __restrict__ outE)
{
  int b = blockIdx.x;
  int t = threadIdx.x;
  float s = Ei[b*N_ + t] + Ei[b*N_ + 256 + t];
  #pragma unroll
  for (int off = 32; off; off >>= 1) s += __shfl_down(s, off, 64);
  __shared__ float ws[4];
  if ((t & 63) == 0) ws[t >> 6] = s;
  __syncthreads();
  if (t == 0) outE[b] = ws[0] + ws[1] + ws[2] + ws[3];
}

extern "C" void kernel_launch(void* const* d_in, const int* in_sizes, int n_in,
                              void* d_out, int out_size, void* d_ws, size_t ws_size,
                              hipStream_t stream)
{
  const float* img = (const float*)d_in[0];
  const float* ew0 = (const float*)d_in[1];
  const float* eb0 = (const float*)d_in[2];
  const float* ew1 = (const float*)d_in[3];
  const float* eb1 = (const float*)d_in[4];
  const float* ew2 = (const float*)d_in[5];
  const float* eb2 = (const float*)d_in[6];
  const float* fw0 = (const float*)d_in[7];
  const float* fb0 = (const float*)d_in[8];
  const float* fw1 = (const float*)d_in[9];
  const float* fb1 = (const float*)d_in[10];
  const float* fw2 = (const float*)d_in[11];
  const float* fb2 = (const float*)d_in[12];
  const float* fw3 = (const float*)d_in[13];
  const float* fb3 = (const float*)d_in[14];

  float* DR = (float*)d_ws;                       // 4096*1600
  float* H1 = DR + (size_t)NPAIR*DRLEN;           // 4096*240
  float* H2 = H1 + (size_t)NPAIR*F0;
  float* H3 = H2 + (size_t)NPAIR*F0;
  float* Ei = H3 + (size_t)NPAIR*F0;              // 4096

  float* out = (float*)d_out;                     // [0..7]=Etot, [8..4103]=Ei

  embed_kernel<<<NPAIR, 128, 0, stream>>>(img, ew0, eb0, ew1, eb1, ew2, eb2, DR);

  dim3 g1(NPAIR/64, (F0 + 63)/64);
  gemm_k<1><<<g1, 256, 0, stream>>>(DR, fw0, fb0, H1, NPAIR, F0, DRLEN);
  gemm_k<1><<<g1, 256, 0, stream>>>(H1, fw1, fb1, H2, NPAIR, F0, F0);
  gemm_k<1><<<g1, 256, 0, stream>>>(H2, fw2, fb2, H3, NPAIR, F0, F0);

  gemv_out<<<NPAIR/4, 256, 0, stream>>>(H3, fw3, fb3, Ei, out + 8);
  etot_k<<<B_, 256, 0, stream>>>(Ei, out);
}

// Round 3
// 398.311 us; speedup vs baseline: 2.7862x; 2.7862x over previous
//
#include <hip/hip_runtime.h>
#include <hip/hip_bf16.h>
#include <math.h>

#define B_ 8
#define N_ 512
#define K_ 128
#define M_ 100
#define NPAIR (B_*N_)    // 4096
#define DRLEN 1600
#define F0 240

#define NLUT 2048
#define LUT_STRIDE 128          // floats per row (100 used, padded)
#define SMAX 1.5f

static __device__ __forceinline__ float tanh_f(float x){
  float xc = fminf(fmaxf(x, -15.f), 15.f);
  float e = __expf(2.f*xc);
  return __fdividef(e - 1.f, e + 1.f);
}

// ---------------------------------------------------------------------------
// LUT build: T[e][m] = G(S_e), S_e = e * SMAX/(NLUT-1). One thread per entry.
// ---------------------------------------------------------------------------
__global__ __launch_bounds__(128) void lut_build(
    const float* __restrict__ ew0, const float* __restrict__ eb0,
    const float* __restrict__ ew1, const float* __restrict__ eb1,
    const float* __restrict__ ew2, const float* __restrict__ eb2,
    float* __restrict__ T)
{
  const int e = blockIdx.x * 128 + threadIdx.x;
  const float S = (float)e * (SMAX / (float)(NLUT - 1));

  float h0[25];
  #pragma unroll
  for (int c = 0; c < 25; c++)
    h0[c] = tanh_f(fmaf(S, ew0[c], eb0[c]));

  float h1[50];
  #pragma unroll
  for (int c = 0; c < 50; c += 2){
    float a0 = eb1[c], a1 = eb1[c+1];
    #pragma unroll
    for (int k = 0; k < 25; k++){
      float h = h0[k];
      a0 = fmaf(h, ew1[k*50 + c],     a0);
      a1 = fmaf(h, ew1[k*50 + c + 1], a1);
    }
    h1[c]   = tanh_f(a0);
    h1[c+1] = tanh_f(a1);
  }

  float* row = T + (size_t)e * LUT_STRIDE;
  for (int c = 0; c < M_; c += 2){
    float a0 = eb2[c], a1 = eb2[c+1];
    float b0 = 0.f, b1v = 0.f;
    #pragma unroll
    for (int k = 0; k < 50; k += 2){
      float ha = h1[k], hb = h1[k+1];
      a0  = fmaf(ha, ew2[k*M_ + c],         a0);
      a1  = fmaf(ha, ew2[k*M_ + c + 1],     a1);
      b0  = fmaf(hb, ew2[(k+1)*M_ + c],     b0);
      b1v = fmaf(hb, ew2[(k+1)*M_ + c + 1], b1v);
    }
    row[c]   = tanh_f(a0 + b0);
    row[c+1] = tanh_f(a1 + b1v);
  }
}

// ---------------------------------------------------------------------------
// Embed: per (b,n) pair. Phase A: S/Ri/LUT-coords. Phase B: tmpB[4][100] via
// LUT lerp (tmpA == tmpB[:, :16]^T algebraically). Phase C: DR[m][h].
// LDS ~= 5 KB -> high occupancy.
// ---------------------------------------------------------------------------
__global__ __launch_bounds__(128) void embed_kernel(
    const float* __restrict__ img, const float* __restrict__ T,
    float* __restrict__ DR)
{
  __shared__ float4 sRi[K_];      // 2 KB
  __shared__ float2 sJW[K_];      // 1 KB  (row index as float, lerp weight)
  __shared__ float  sB[4][M_];    // 1.6 KB

  const int pair = blockIdx.x;
  const int t = threadIdx.x;

  // ---- phase A ----
  {
    float4 v = *(const float4*)(img + ((size_t)pair*K_ + t)*4);
    float x = v.x, y = v.y, z = v.z, fl = v.w;
    float R = fmaf(x, x, fmaf(y, y, z*z));
    bool mask = fl > 0.f;
    bool lt10 = R < 10.f;
    float safe = (R == 0.f) ? 1.f : R;
    float Sc = 0.5f*cosf(0.20943951023931953f*(R - 10.f)) + 0.5f;  // pi/15
    float S;
    if (mask && lt10)            S = 1.f/safe;
    else if (!lt10 && R < 25.f)  S = Sc;
    else                         S = 0.f;
    float coef = mask ? S/safe : 0.f;
    sRi[t] = make_float4(S, coef*x, coef*y, coef*z);

    float fidx = fminf(S, SMAX) * ((float)(NLUT - 1) / SMAX);
    float fi = floorf(fidx);
    int i = (int)fi;
    float w = fidx - fi;
    if (i > NLUT - 2){ i = NLUT - 2; w = 1.f; }
    sJW[t] = make_float2((float)i, w);
  }
  __syncthreads();

  // ---- phase B: tmpB[f][m] = sum_j Ri[j][f] * lerp(T[i_j][m], T[i_j+1][m]) ----
  if (t < M_){
    const int m = t;
    float a0 = 0.f, a1 = 0.f, a2 = 0.f, a3 = 0.f;
    #pragma unroll 4
    for (int j = 0; j < K_; j++){
      float2 jw = sJW[j];
      float4 ri = sRi[j];
      const float* r0 = T + (size_t)((int)jw.x) * LUT_STRIDE + m;
      float t0 = r0[0];
      float t1 = r0[LUT_STRIDE];
      float g = fmaf(jw.y, t1 - t0, t0);
      a0 = fmaf(ri.x, g, a0);
      a1 = fmaf(ri.y, g, a1);
      a2 = fmaf(ri.z, g, a2);
      a3 = fmaf(ri.w, g, a3);
    }
    sB[0][m] = a0; sB[1][m] = a1; sB[2][m] = a2; sB[3][m] = a3;
  }
  __syncthreads();

  // ---- phase C: DR[m][h] = sum_f sB[f][m] * sB[f][h]  (m<16) ----
  float* drp = DR + (size_t)pair*DRLEN;
  for (int o = t; o < DRLEN; o += 128){
    int m = o / M_, h = o % M_;
    float d = sB[0][m]*sB[0][h] + sB[1][m]*sB[1][h]
            + sB[2][m]*sB[2][h] + sB[3][m]*sB[3][h];
    drp[o] = d;
  }
}

// ---------------------------------------------------------------------------
// GEMM: Y[M,N] = act(X[M,K] @ W[K,N] + bias), all f32.
// 64x64 tile, 256 threads, 4x4 per thread. K % 16 == 0, M % 64 == 0.
// ---------------------------------------------------------------------------
template<int TANH>
__global__ __launch_bounds__(256) void gemm_k(
    const float* __restrict__ X, const float* __restrict__ W,
    const float* __restrict__ bias, float* __restrict__ Y,
    int M, int N, int K)
{
  __shared__ float Xs[16][68];   // [k][row]
  __shared__ float Ws[16][68];   // [k][col]
  const int tid = threadIdx.x;
  const int tx = tid & 15, ty = tid >> 4;
  const int row0 = blockIdx.x * 64;
  const int col0 = blockIdx.y * 64;
  const int lk = tid & 15, lr = tid >> 4;   // X loader
  const int ln = tid & 63, lw = tid >> 6;   // W loader
  float acc[4][4] = {};

  for (int kt = 0; kt < K; kt += 16){
    #pragma unroll
    for (int i = 0; i < 4; i++){
      int r = lr + i*16;
      Xs[lk][r] = X[(size_t)(row0 + r)*K + kt + lk];
    }
    #pragma unroll
    for (int i = 0; i < 4; i++){
      int kk = lw + i*4;
      int c = col0 + ln;
      Ws[kk][ln] = (c < N) ? W[(size_t)(kt + kk)*N + c] : 0.f;
    }
    __syncthreads();
    #pragma unroll
    for (int kk = 0; kk < 16; kk++){
      float a[4], b[4];
      #pragma unroll
      for (int i = 0; i < 4; i++) a[i] = Xs[kk][ty*4 + i];
      #pragma unroll
      for (int i = 0; i < 4; i++) b[i] = Ws[kk][tx*4 + i];
      #pragma unroll
      for (int i = 0; i < 4; i++)
        #pragma unroll
        for (int jj = 0; jj < 4; jj++)
          acc[i][jj] = fmaf(a[i], b[jj], acc[i][jj]);
    }
    __syncthreads();
  }

  #pragma unroll
  for (int i = 0; i < 4; i++){
    int r = row0 + ty*4 + i;
    #pragma unroll
    for (int jj = 0; jj < 4; jj++){
      int c = col0 + tx*4 + jj;
      if (c < N){
        float v = acc[i][jj] + bias[c];
        if (TANH) v = tanh_f(v);
        Y[(size_t)r*N + c] = v;
      }
    }
  }
}

// ---------------------------------------------------------------------------
// GEMV: Ei[m] = H[m,:240] . w3 + b3 ; one wave per row.
// ---------------------------------------------------------------------------
__global__ __launch_bounds__(256) void gemv_out(
    const float* __restrict__ H, const float* __restrict__ w3,
    const float* __restrict__ b3, float* __restrict__ Ei,
    float* __restrict__ outEi)
{
  int row  = (blockIdx.x * 256 + threadIdx.x) >> 6;
  int lane = threadIdx.x & 63;
  const float* hp = H + (size_t)row * F0;
  float a = 0.f;
  for (int k = lane; k < F0; k += 64) a = fmaf(hp[k], w3[k], a);
  #pragma unroll
  for (int off = 32; off; off >>= 1) a += __shfl_down(a, off, 64);
  if (lane == 0){
    float e = a + b3[0];
    Ei[row] = e;
    outEi[row] = e;
  }
}

// ---------------------------------------------------------------------------
// Etot[b] = sum_n Ei[b,n]
// ---------------------------------------------------------------------------
__global__ __launch_bounds__(256) void etot_k(
    const float* __restrict__ Ei, float* __restrict__ outE)
{
  int b = blockIdx.x;
  int t = threadIdx.x;
  float s = Ei[b*N_ + t] + Ei[b*N_ + 256 + t];
  #pragma unroll
  for (int off = 32; off; off >>= 1) s += __shfl_down(s, off, 64);
  __shared__ float ws[4];
  if ((t & 63) == 0) ws[t >> 6] = s;
  __syncthreads();
  if (t == 0) outE[b] = ws[0] + ws[1] + ws[2] + ws[3];
}

extern "C" void kernel_launch(void* const* d_in, const int* in_sizes, int n_in,
                              void* d_out, int out_size, void* d_ws, size_t ws_size,
                              hipStream_t stream)
{
  const float* img = (const float*)d_in[0];
  const float* ew0 = (const float*)d_in[1];
  const float* eb0 = (const float*)d_in[2];
  const float* ew1 = (const float*)d_in[3];
  const float* eb1 = (const float*)d_in[4];
  const float* ew2 = (const float*)d_in[5];
  const float* eb2 = (const float*)d_in[6];
  const float* fw0 = (const float*)d_in[7];
  const float* fb0 = (const float*)d_in[8];
  const float* fw1 = (const float*)d_in[9];
  const float* fb1 = (const float*)d_in[10];
  const float* fw2 = (const float*)d_in[11];
  const float* fb2 = (const float*)d_in[12];
  const float* fw3 = (const float*)d_in[13];
  const float* fb3 = (const float*)d_in[14];

  float* DR = (float*)d_ws;                       // 4096*1600
  float* H1 = DR + (size_t)NPAIR*DRLEN;           // 4096*240
  float* H2 = H1 + (size_t)NPAIR*F0;
  float* H3 = H2 + (size_t)NPAIR*F0;
  float* Ei = H3 + (size_t)NPAIR*F0;              // 4096
  // LUT aliases H1: only live between lut_build and embed; gemm1 writes H1
  // afterwards (stream-ordered, safe). 2048*128 floats = 1 MB < H1's 3.9 MB.
  float* LUT = H1;

  float* out = (float*)d_out;                     // [0..7]=Etot, [8..4103]=Ei

  lut_build<<<NLUT/128, 128, 0, stream>>>(ew0, eb0, ew1, eb1, ew2, eb2, LUT);
  embed_kernel<<<NPAIR, 128, 0, stream>>>(img, LUT, DR);

  dim3 g1(NPAIR/64, (F0 + 63)/64);
  gemm_k<1><<<g1, 256, 0, stream>>>(DR, fw0, fb0, H1, NPAIR, F0, DRLEN);
  gemm_k<1><<<g1, 256, 0, stream>>>(H1, fw1, fb1, H2, NPAIR, F0, F0);
  gemm_k<1><<<g1, 256, 0, stream>>>(H2, fw2, fb2, H3, NPAIR, F0, F0);

  gemv_out<<<NPAIR/4, 256, 0, stream>>>(H3, fw3, fb3, Ei, out + 8);
  etot_k<<<B_, 256, 0, stream>>>(Ei, out);
}

// Round 4
// 267.982 us; speedup vs baseline: 4.1412x; 1.4863x over previous
//
#include <hip/hip_runtime.h>
#include <hip/hip_bf16.h>
#include <math.h>

#define B_ 8
#define N_ 512
#define K_ 128
#define M_ 100
#define NPAIR (B_*N_)    // 4096
#define DRLEN 1600
#define F0 240
#define NPAD 256

#define NLUT 2048
#define LUT_STRIDE 128
#define SMAX 1.5f

using bf16x8 = __attribute__((ext_vector_type(8))) __bf16;
using f32x4  = __attribute__((ext_vector_type(4))) float;

static __device__ __forceinline__ float tanh_f(float x){
  float xc = fminf(fmaxf(x, -15.f), 15.f);
  float e = __expf(2.f*xc);
  return __fdividef(e - 1.f, e + 1.f);
}

// ---------------------------------------------------------------------------
// LUT build: T[e][m] = G(S_e). One thread per entry.
// ---------------------------------------------------------------------------
__global__ __launch_bounds__(128) void lut_build(
    const float* __restrict__ ew0, const float* __restrict__ eb0,
    const float* __restrict__ ew1, const float* __restrict__ eb1,
    const float* __restrict__ ew2, const float* __restrict__ eb2,
    float* __restrict__ T)
{
  const int e = blockIdx.x * 128 + threadIdx.x;
  const float S = (float)e * (SMAX / (float)(NLUT - 1));

  float h0[25];
  #pragma unroll
  for (int c = 0; c < 25; c++)
    h0[c] = tanh_f(fmaf(S, ew0[c], eb0[c]));

  float h1[50];
  #pragma unroll
  for (int c = 0; c < 50; c += 2){
    float a0 = eb1[c], a1 = eb1[c+1];
    #pragma unroll
    for (int k = 0; k < 25; k++){
      float h = h0[k];
      a0 = fmaf(h, ew1[k*50 + c],     a0);
      a1 = fmaf(h, ew1[k*50 + c + 1], a1);
    }
    h1[c]   = tanh_f(a0);
    h1[c+1] = tanh_f(a1);
  }

  float* row = T + (size_t)e * LUT_STRIDE;
  for (int c = 0; c < M_; c += 2){
    float a0 = eb2[c], a1 = eb2[c+1];
    float b0 = 0.f, b1v = 0.f;
    #pragma unroll
    for (int k = 0; k < 50; k += 2){
      float ha = h1[k], hb = h1[k+1];
      a0  = fmaf(ha, ew2[k*M_ + c],         a0);
      a1  = fmaf(ha, ew2[k*M_ + c + 1],     a1);
      b0  = fmaf(hb, ew2[(k+1)*M_ + c],     b0);
      b1v = fmaf(hb, ew2[(k+1)*M_ + c + 1], b1v);
    }
    row[c]   = tanh_f(a0 + b0);
    row[c+1] = tanh_f(a1 + b1v);
  }
}

// ---------------------------------------------------------------------------
// Weight prep: dst[n][k] = src[k][n] (f32 -> bf16, zero-padded to [256][Kdst])
// ---------------------------------------------------------------------------
__global__ __launch_bounds__(256) void prep_wT(
    const float* __restrict__ src, __hip_bfloat16* __restrict__ dst,
    int Ksrc, int Kdst, int Nsrc)
{
  int idx = blockIdx.x*256 + threadIdx.x;
  if (idx >= NPAD*Kdst) return;
  int n = idx / Kdst, k = idx % Kdst;
  float v = (n < Nsrc && k < Ksrc) ? src[(size_t)k*Nsrc + n] : 0.f;
  dst[idx] = __float2bfloat16(v);
}

__global__ __launch_bounds__(256) void prep_bias(
    const float* __restrict__ s0, const float* __restrict__ s1,
    const float* __restrict__ s2,
    float* __restrict__ d0, float* __restrict__ d1, float* __restrict__ d2)
{
  int c = threadIdx.x;
  d0[c] = (c < F0) ? s0[c] : 0.f;
  d1[c] = (c < F0) ? s1[c] : 0.f;
  d2[c] = (c < F0) ? s2[c] : 0.f;
}

// ---------------------------------------------------------------------------
// Embed: per (b,n) pair; LUT lerp; DR out in bf16 [pair][1600].
// ---------------------------------------------------------------------------
__global__ __launch_bounds__(128) void embed_kernel(
    const float* __restrict__ img, const float* __restrict__ T,
    __hip_bfloat16* __restrict__ DR)
{
  __shared__ float4 sRi[K_];
  __shared__ float2 sJW[K_];
  __shared__ float  sB[4][M_];

  const int pair = blockIdx.x;
  const int t = threadIdx.x;

  {
    float4 v = *(const float4*)(img + ((size_t)pair*K_ + t)*4);
    float x = v.x, y = v.y, z = v.z, fl = v.w;
    float R = fmaf(x, x, fmaf(y, y, z*z));
    bool mask = fl > 0.f;
    bool lt10 = R < 10.f;
    float safe = (R == 0.f) ? 1.f : R;
    float Sc = 0.5f*cosf(0.20943951023931953f*(R - 10.f)) + 0.5f;
    float S;
    if (mask && lt10)            S = 1.f/safe;
    else if (!lt10 && R < 25.f)  S = Sc;
    else                         S = 0.f;
    float coef = mask ? S/safe : 0.f;
    sRi[t] = make_float4(S, coef*x, coef*y, coef*z);

    float fidx = fminf(S, SMAX) * ((float)(NLUT - 1) / SMAX);
    float fi = floorf(fidx);
    int i = (int)fi;
    float w = fidx - fi;
    if (i > NLUT - 2){ i = NLUT - 2; w = 1.f; }
    sJW[t] = make_float2((float)i, w);
  }
  __syncthreads();

  if (t < M_){
    const int m = t;
    float a0 = 0.f, a1 = 0.f, a2 = 0.f, a3 = 0.f;
    #pragma unroll 4
    for (int j = 0; j < K_; j++){
      float2 jw = sJW[j];
      float4 ri = sRi[j];
      const float* r0 = T + (size_t)((int)jw.x) * LUT_STRIDE + m;
      float t0 = r0[0];
      float t1 = r0[LUT_STRIDE];
      float g = fmaf(jw.y, t1 - t0, t0);
      a0 = fmaf(ri.x, g, a0);
      a1 = fmaf(ri.y, g, a1);
      a2 = fmaf(ri.z, g, a2);
      a3 = fmaf(ri.w, g, a3);
    }
    sB[0][m] = a0; sB[1][m] = a1; sB[2][m] = a2; sB[3][m] = a3;
  }
  __syncthreads();

  __hip_bfloat16* drp = DR + (size_t)pair*DRLEN;
  for (int o = t; o < DRLEN; o += 128){
    int m = o / M_, h = o % M_;
    float d = sB[0][m]*sB[0][h] + sB[1][m]*sB[1][h]
            + sB[2][m]*sB[2][h] + sB[3][m]*sB[3][h];
    drp[o] = __float2bfloat16(d);
  }
}

// ---------------------------------------------------------------------------
// MFMA GEMM: Y[M][256] = tanh(A[M][K] @ Bt^T + bias), bf16 in, bf16 out.
// A row-major [M][K] bf16; Bt row-major [256][K] bf16 (i.e. W^T, zero-padded).
// Block: 256 thr = 4 waves (2x2), wave tile 32x64, block tile 64x128.
// Grid: (M/64, 2).
// ---------------------------------------------------------------------------
__global__ __launch_bounds__(256) void gemm_mfma(
    const __hip_bfloat16* __restrict__ A_, const __hip_bfloat16* __restrict__ Bt_,
    const float* __restrict__ bias, __hip_bfloat16* __restrict__ Y, int K)
{
  const __bf16* A  = (const __bf16*)A_;
  const __bf16* Bt = (const __bf16*)Bt_;

  const int tid = threadIdx.x;
  const int lane = tid & 63, wave = tid >> 6;
  const int wm = wave & 1, wn = wave >> 1;
  const int row0 = blockIdx.x*64 + wm*32;
  const int col0 = blockIdx.y*128 + wn*64;
  const int l15 = lane & 15, q = lane >> 4;

  f32x4 acc[2][4] = {};

  const __bf16* pa0 = A  + (size_t)(row0 + l15)*K + q*8;
  const __bf16* pa1 = pa0 + (size_t)16*K;
  const __bf16* pb  = Bt + (size_t)(col0 + l15)*K + q*8;
  const size_t bstep = (size_t)16*K;

  for (int k0 = 0; k0 < K; k0 += 32){
    bf16x8 a0 = *(const bf16x8*)(pa0 + k0);
    bf16x8 a1 = *(const bf16x8*)(pa1 + k0);
    bf16x8 b0 = *(const bf16x8*)(pb + k0);
    bf16x8 b1 = *(const bf16x8*)(pb + bstep + k0);
    bf16x8 b2 = *(const bf16x8*)(pb + 2*bstep + k0);
    bf16x8 b3 = *(const bf16x8*)(pb + 3*bstep + k0);
    acc[0][0] = __builtin_amdgcn_mfma_f32_16x16x32_bf16(a0, b0, acc[0][0], 0,0,0);
    acc[1][0] = __builtin_amdgcn_mfma_f32_16x16x32_bf16(a1, b0, acc[1][0], 0,0,0);
    acc[0][1] = __builtin_amdgcn_mfma_f32_16x16x32_bf16(a0, b1, acc[0][1], 0,0,0);
    acc[1][1] = __builtin_amdgcn_mfma_f32_16x16x32_bf16(a1, b1, acc[1][1], 0,0,0);
    acc[0][2] = __builtin_amdgcn_mfma_f32_16x16x32_bf16(a0, b2, acc[0][2], 0,0,0);
    acc[1][2] = __builtin_amdgcn_mfma_f32_16x16x32_bf16(a1, b2, acc[1][2], 0,0,0);
    acc[0][3] = __builtin_amdgcn_mfma_f32_16x16x32_bf16(a0, b3, acc[0][3], 0,0,0);
    acc[1][3] = __builtin_amdgcn_mfma_f32_16x16x32_bf16(a1, b3, acc[1][3], 0,0,0);
  }

  #pragma unroll
  for (int i = 0; i < 2; i++){
    #pragma unroll
    for (int j = 0; j < 4; j++){
      int c = col0 + j*16 + l15;
      float bs = bias[c];
      #pragma unroll
      for (int r = 0; r < 4; r++){
        int rr = row0 + i*16 + q*4 + r;
        float v = tanh_f(acc[i][j][r] + bs);
        Y[(size_t)rr*NPAD + c] = __float2bfloat16(v);
      }
    }
  }
}

// ---------------------------------------------------------------------------
// GEMV: Ei[m] = H[m,:240] . w3 + b3 ; one wave per row. H is bf16 [m][256].
// ---------------------------------------------------------------------------
__global__ __launch_bounds__(256) void gemv_out(
    const __hip_bfloat16* __restrict__ H, const float* __restrict__ w3,
    const float* __restrict__ b3, float* __restrict__ Ei,
    float* __restrict__ outEi)
{
  int row  = (blockIdx.x * 256 + threadIdx.x) >> 6;
  int lane = threadIdx.x & 63;
  const __hip_bfloat16* hp = H + (size_t)row * NPAD;
  float a = 0.f;
  for (int k = lane; k < F0; k += 64) a = fmaf(__bfloat162float(hp[k]), w3[k], a);
  #pragma unroll
  for (int off = 32; off; off >>= 1) a += __shfl_down(a, off, 64);
  if (lane == 0){
    float e = a + b3[0];
    Ei[row] = e;
    outEi[row] = e;
  }
}

__global__ __launch_bounds__(256) void etot_k(
    const float* __restrict__ Ei, float* __restrict__ outE)
{
  int b = blockIdx.x;
  int t = threadIdx.x;
  float s = Ei[b*N_ + t] + Ei[b*N_ + 256 + t];
  #pragma unroll
  for (int off = 32; off; off >>= 1) s += __shfl_down(s, off, 64);
  __shared__ float ws[4];
  if ((t & 63) == 0) ws[t >> 6] = s;
  __syncthreads();
  if (t == 0) outE[b] = ws[0] + ws[1] + ws[2] + ws[3];
}

extern "C" void kernel_launch(void* const* d_in, const int* in_sizes, int n_in,
                              void* d_out, int out_size, void* d_ws, size_t ws_size,
                              hipStream_t stream)
{
  const float* img = (const float*)d_in[0];
  const float* ew0 = (const float*)d_in[1];
  const float* eb0 = (const float*)d_in[2];
  const float* ew1 = (const float*)d_in[3];
  const float* eb1 = (const float*)d_in[4];
  const float* ew2 = (const float*)d_in[5];
  const float* eb2 = (const float*)d_in[6];
  const float* fw0 = (const float*)d_in[7];
  const float* fb0 = (const float*)d_in[8];
  const float* fw1 = (const float*)d_in[9];
  const float* fb1 = (const float*)d_in[10];
  const float* fw2 = (const float*)d_in[11];
  const float* fb2 = (const float*)d_in[12];
  const float* fw3 = (const float*)d_in[13];
  const float* fb3 = (const float*)d_in[14];

  char* w = (char*)d_ws;
  __hip_bfloat16* DRb = (__hip_bfloat16*)(w);                 // 13107200 B
  __hip_bfloat16* H1b = (__hip_bfloat16*)(w + 13107200);      // 2097152 B
  __hip_bfloat16* H2b = (__hip_bfloat16*)(w + 15204352);
  __hip_bfloat16* H3b = (__hip_bfloat16*)(w + 17301504);
  __hip_bfloat16* W0T = (__hip_bfloat16*)(w + 19398656);      // 819200 B
  __hip_bfloat16* W1T = (__hip_bfloat16*)(w + 20217856);      // 131072 B
  __hip_bfloat16* W2T = (__hip_bfloat16*)(w + 20348928);      // 131072 B
  float* b0p = (float*)(w + 20480000);                        // 1024 B
  float* b1p = (float*)(w + 20481024);
  float* b2p = (float*)(w + 20482048);
  float* LUT = (float*)(w + 20483072);                        // 1048576 B
  float* Ei  = (float*)(w + 21531648);                        // 16384 B

  float* out = (float*)d_out;                                 // [0..7]=Etot, [8..]=Ei

  prep_wT<<<(NPAD*DRLEN + 255)/256, 256, 0, stream>>>(fw0, W0T, DRLEN, DRLEN, F0);
  prep_wT<<<(NPAD*NPAD + 255)/256, 256, 0, stream>>>(fw1, W1T, F0, NPAD, F0);
  prep_wT<<<(NPAD*NPAD + 255)/256, 256, 0, stream>>>(fw2, W2T, F0, NPAD, F0);
  prep_bias<<<1, 256, 0, stream>>>(fb0, fb1, fb2, b0p, b1p, b2p);

  lut_build<<<NLUT/128, 128, 0, stream>>>(ew0, eb0, ew1, eb1, ew2, eb2, LUT);
  embed_kernel<<<NPAIR, 128, 0, stream>>>(img, LUT, DRb);

  dim3 gg(NPAIR/64, NPAD/128);
  gemm_mfma<<<gg, 256, 0, stream>>>(DRb, W0T, b0p, H1b, DRLEN);
  gemm_mfma<<<gg, 256, 0, stream>>>(H1b, W1T, b1p, H2b, NPAD);
  gemm_mfma<<<gg, 256, 0, stream>>>(H2b, W2T, b2p, H3b, NPAD);

  gemv_out<<<NPAIR/4, 256, 0, stream>>>(H3b, fw3, fb3, Ei, out + 8);
  etot_k<<<B_, 256, 0, stream>>>(Ei, out);
}

// Round 5
// 178.617 us; speedup vs baseline: 6.2132x; 1.5003x over previous
//
#include <hip/hip_runtime.h>
#include <hip/hip_bf16.h>
#include <math.h>

#define B_ 8
#define N_ 512
#define K_ 128
#define M_ 100
#define NPAIR (B_*N_)    // 4096
#define DRLEN 1600
#define F0 240
#define NPAD 256

#define NLUT 2048
#define LUT_STRIDE 128
#define SMAX 1.5f
#define EPB 8            // LUT entries per block

using bf16x8 = __attribute__((ext_vector_type(8))) __bf16;
using f32x4  = __attribute__((ext_vector_type(4))) float;

static __device__ __forceinline__ float tanh_f(float x){
  float xc = fminf(fmaxf(x, -15.f), 15.f);
  float e = __expf(2.f*xc);
  return __fdividef(e - 1.f, e + 1.f);
}

// ---------------------------------------------------------------------------
// Parallel LUT build: block = EPB entries x 256 threads, h0/h1 in LDS.
// T[e][m] = G(S_e), S_e = e * SMAX/(NLUT-1).
// ---------------------------------------------------------------------------
__global__ __launch_bounds__(256) void lut_build_par(
    const float* __restrict__ ew0, const float* __restrict__ eb0,
    const float* __restrict__ ew1, const float* __restrict__ eb1,
    const float* __restrict__ ew2, const float* __restrict__ eb2,
    float* __restrict__ T)
{
  __shared__ float sh0[EPB][26];
  __shared__ float sh1[EPB][52];
  const int e0 = blockIdx.x * EPB;
  const int t = threadIdx.x;

  // phase 1: h0 = tanh(S*w0 + b0)  (EPB*25 = 200 independent elems)
  if (t < EPB*25){
    int e = t / 25, c = t % 25;
    float S = (float)(e0 + e) * (SMAX / (float)(NLUT - 1));
    sh0[e][c] = tanh_f(fmaf(S, ew0[c], eb0[c]));
  }
  __syncthreads();

  // phase 2: h1 = tanh(h0 @ w1 + b1)  (EPB*50 = 400 outputs, 25 MACs each)
  for (int o = t; o < EPB*50; o += 256){
    int e = o / 50, c = o % 50;
    float a = eb1[c], b = 0.f;
    #pragma unroll
    for (int k = 0; k < 24; k += 2){
      a = fmaf(sh0[e][k],   ew1[k*50 + c],     a);
      b = fmaf(sh0[e][k+1], ew1[(k+1)*50 + c], b);
    }
    a = fmaf(sh0[e][24], ew1[24*50 + c], a);
    sh1[e][c] = tanh_f(a + b);
  }
  __syncthreads();

  // phase 3: G = tanh(h1 @ w2 + b2)  (EPB*100 = 800 outputs, 50 MACs each)
  for (int o = t; o < EPB*M_; o += 256){
    int e = o / M_, c = o % M_;
    float a = eb2[c], b = 0.f;
    #pragma unroll
    for (int k = 0; k < 50; k += 2){
      a = fmaf(sh1[e][k],   ew2[k*M_ + c],     a);
      b = fmaf(sh1[e][k+1], ew2[(k+1)*M_ + c], b);
    }
    T[(size_t)(e0 + e)*LUT_STRIDE + c] = tanh_f(a + b);
  }
}

// ---------------------------------------------------------------------------
// Fused prep: W0T/W1T/W2T transpose+bf16 (zero-padded [256][K]) + biases.
// Grid-region dispatch over 541440 linear elements.
// ---------------------------------------------------------------------------
__global__ __launch_bounds__(256) void prep_all(
    const float* __restrict__ fw0, const float* __restrict__ fw1,
    const float* __restrict__ fw2,
    const float* __restrict__ fb0, const float* __restrict__ fb1,
    const float* __restrict__ fb2,
    __hip_bfloat16* __restrict__ W0T, __hip_bfloat16* __restrict__ W1T,
    __hip_bfloat16* __restrict__ W2T,
    float* __restrict__ b0p, float* __restrict__ b1p, float* __restrict__ b2p)
{
  int idx = blockIdx.x*256 + threadIdx.x;
  if (idx < NPAD*DRLEN){                                  // W0T [256][1600]
    int n = idx / DRLEN, k = idx % DRLEN;
    W0T[idx] = __float2bfloat16((n < F0) ? fw0[(size_t)k*F0 + n] : 0.f);
  } else if (idx < NPAD*DRLEN + NPAD*NPAD){               // W1T [256][256]
    int j = idx - NPAD*DRLEN;
    int n = j / NPAD, k = j % NPAD;
    W1T[j] = __float2bfloat16((n < F0 && k < F0) ? fw1[(size_t)k*F0 + n] : 0.f);
  } else if (idx < NPAD*DRLEN + 2*NPAD*NPAD){             // W2T [256][256]
    int j = idx - NPAD*DRLEN - NPAD*NPAD;
    int n = j / NPAD, k = j % NPAD;
    W2T[j] = __float2bfloat16((n < F0 && k < F0) ? fw2[(size_t)k*F0 + n] : 0.f);
  } else if (idx < NPAD*DRLEN + 2*NPAD*NPAD + 3*NPAD){    // biases
    int j = idx - NPAD*DRLEN - 2*NPAD*NPAD;
    int which = j / NPAD, c = j % NPAD;
    const float* s = (which == 0) ? fb0 : (which == 1) ? fb1 : fb2;
    float* d = (which == 0) ? b0p : (which == 1) ? b1p : b2p;
    d[c] = (c < F0) ? s[c] : 0.f;
  }
}

// ---------------------------------------------------------------------------
// Embed: per (b,n) pair; LUT lerp; DR out in bf16 [pair][1600].
// ---------------------------------------------------------------------------
__global__ __launch_bounds__(128) void embed_kernel(
    const float* __restrict__ img, const float* __restrict__ T,
    __hip_bfloat16* __restrict__ DR)
{
  __shared__ float4 sRi[K_];
  __shared__ float2 sJW[K_];
  __shared__ float  sB[4][M_];

  const int pair = blockIdx.x;
  const int t = threadIdx.x;

  {
    float4 v = *(const float4*)(img + ((size_t)pair*K_ + t)*4);
    float x = v.x, y = v.y, z = v.z, fl = v.w;
    float R = fmaf(x, x, fmaf(y, y, z*z));
    bool mask = fl > 0.f;
    bool lt10 = R < 10.f;
    float safe = (R == 0.f) ? 1.f : R;
    float Sc = 0.5f*cosf(0.20943951023931953f*(R - 10.f)) + 0.5f;
    float S;
    if (mask && lt10)            S = 1.f/safe;
    else if (!lt10 && R < 25.f)  S = Sc;
    else                         S = 0.f;
    float coef = mask ? S/safe : 0.f;
    sRi[t] = make_float4(S, coef*x, coef*y, coef*z);

    float fidx = fminf(S, SMAX) * ((float)(NLUT - 1) / SMAX);
    float fi = floorf(fidx);
    int i = (int)fi;
    float w = fidx - fi;
    if (i > NLUT - 2){ i = NLUT - 2; w = 1.f; }
    sJW[t] = make_float2((float)i, w);
  }
  __syncthreads();

  if (t < M_){
    const int m = t;
    float a0 = 0.f, a1 = 0.f, a2 = 0.f, a3 = 0.f;
    #pragma unroll 4
    for (int j = 0; j < K_; j++){
      float2 jw = sJW[j];
      float4 ri = sRi[j];
      const float* r0 = T + (size_t)((int)jw.x) * LUT_STRIDE + m;
      float t0 = r0[0];
      float t1 = r0[LUT_STRIDE];
      float g = fmaf(jw.y, t1 - t0, t0);
      a0 = fmaf(ri.x, g, a0);
      a1 = fmaf(ri.y, g, a1);
      a2 = fmaf(ri.z, g, a2);
      a3 = fmaf(ri.w, g, a3);
    }
    sB[0][m] = a0; sB[1][m] = a1; sB[2][m] = a2; sB[3][m] = a3;
  }
  __syncthreads();

  __hip_bfloat16* drp = DR + (size_t)pair*DRLEN;
  for (int o = t; o < DRLEN; o += 128){
    int m = o / M_, h = o % M_;
    float d = sB[0][m]*sB[0][h] + sB[1][m]*sB[1][h]
            + sB[2][m]*sB[2][h] + sB[3][m]*sB[3][h];
    drp[o] = __float2bfloat16(d);
  }
}

// ---------------------------------------------------------------------------
// MFMA GEMM: Y[M][256] = tanh(A[M][K] @ Bt^T + bias), bf16 in, bf16 out.
// A row-major [M][K]; Bt row-major [256][K] (W^T, zero-padded).
// Block: 256 thr = 4 waves (2x2), wave tile 32x64, block tile 64x128.
// ---------------------------------------------------------------------------
__global__ __launch_bounds__(256) void gemm_mfma(
    const __hip_bfloat16* __restrict__ A_, const __hip_bfloat16* __restrict__ Bt_,
    const float* __restrict__ bias, __hip_bfloat16* __restrict__ Y, int K)
{
  const __bf16* A  = (const __bf16*)A_;
  const __bf16* Bt = (const __bf16*)Bt_;

  const int tid = threadIdx.x;
  const int lane = tid & 63, wave = tid >> 6;
  const int wm = wave & 1, wn = wave >> 1;
  const int row0 = blockIdx.x*64 + wm*32;
  const int col0 = blockIdx.y*128 + wn*64;
  const int l15 = lane & 15, q = lane >> 4;

  f32x4 acc[2][4] = {};

  const __bf16* pa0 = A  + (size_t)(row0 + l15)*K + q*8;
  const __bf16* pa1 = pa0 + (size_t)16*K;
  const __bf16* pb  = Bt + (size_t)(col0 + l15)*K + q*8;
  const size_t bstep = (size_t)16*K;

  for (int k0 = 0; k0 < K; k0 += 32){
    bf16x8 a0 = *(const bf16x8*)(pa0 + k0);
    bf16x8 a1 = *(const bf16x8*)(pa1 + k0);
    bf16x8 b0 = *(const bf16x8*)(pb + k0);
    bf16x8 b1 = *(const bf16x8*)(pb + bstep + k0);
    bf16x8 b2 = *(const bf16x8*)(pb + 2*bstep + k0);
    bf16x8 b3 = *(const bf16x8*)(pb + 3*bstep + k0);
    acc[0][0] = __builtin_amdgcn_mfma_f32_16x16x32_bf16(a0, b0, acc[0][0], 0,0,0);
    acc[1][0] = __builtin_amdgcn_mfma_f32_16x16x32_bf16(a1, b0, acc[1][0], 0,0,0);
    acc[0][1] = __builtin_amdgcn_mfma_f32_16x16x32_bf16(a0, b1, acc[0][1], 0,0,0);
    acc[1][1] = __builtin_amdgcn_mfma_f32_16x16x32_bf16(a1, b1, acc[1][1], 0,0,0);
    acc[0][2] = __builtin_amdgcn_mfma_f32_16x16x32_bf16(a0, b2, acc[0][2], 0,0,0);
    acc[1][2] = __builtin_amdgcn_mfma_f32_16x16x32_bf16(a1, b2, acc[1][2], 0,0,0);
    acc[0][3] = __builtin_amdgcn_mfma_f32_16x16x32_bf16(a0, b3, acc[0][3], 0,0,0);
    acc[1][3] = __builtin_amdgcn_mfma_f32_16x16x32_bf16(a1, b3, acc[1][3], 0,0,0);
  }

  #pragma unroll
  for (int i = 0; i < 2; i++){
    #pragma unroll
    for (int j = 0; j < 4; j++){
      int c = col0 + j*16 + l15;
      float bs = bias[c];
      #pragma unroll
      for (int r = 0; r < 4; r++){
        int rr = row0 + i*16 + q*4 + r;
        float v = tanh_f(acc[i][j][r] + bs);
        Y[(size_t)rr*NPAD + c] = __float2bfloat16(v);
      }
    }
  }
}

// ---------------------------------------------------------------------------
// GEMV: Ei[m] = H[m,:240] . w3 + b3 ; one wave per row. H is bf16 [m][256].
// ---------------------------------------------------------------------------
__global__ __launch_bounds__(256) void gemv_out(
    const __hip_bfloat16* __restrict__ H, const float* __restrict__ w3,
    const float* __restrict__ b3, float* __restrict__ Ei,
    float* __restrict__ outEi)
{
  int row  = (blockIdx.x * 256 + threadIdx.x) >> 6;
  int lane = threadIdx.x & 63;
  const __hip_bfloat16* hp = H + (size_t)row * NPAD;
  float a = 0.f;
  for (int k = lane; k < F0; k += 64) a = fmaf(__bfloat162float(hp[k]), w3[k], a);
  #pragma unroll
  for (int off = 32; off; off >>= 1) a += __shfl_down(a, off, 64);
  if (lane == 0){
    float e = a + b3[0];
    Ei[row] = e;
    outEi[row] = e;
  }
}

__global__ __launch_bounds__(256) void etot_k(
    const float* __restrict__ Ei, float* __restrict__ outE)
{
  int b = blockIdx.x;
  int t = threadIdx.x;
  float s = Ei[b*N_ + t] + Ei[b*N_ + 256 + t];
  #pragma unroll
  for (int off = 32; off; off >>= 1) s += __shfl_down(s, off, 64);
  __shared__ float ws[4];
  if ((t & 63) == 0) ws[t >> 6] = s;
  __syncthreads();
  if (t == 0) outE[b] = ws[0] + ws[1] + ws[2] + ws[3];
}

extern "C" void kernel_launch(void* const* d_in, const int* in_sizes, int n_in,
                              void* d_out, int out_size, void* d_ws, size_t ws_size,
                              hipStream_t stream)
{
  const float* img = (const float*)d_in[0];
  const float* ew0 = (const float*)d_in[1];
  const float* eb0 = (const float*)d_in[2];
  const float* ew1 = (const float*)d_in[3];
  const float* eb1 = (const float*)d_in[4];
  const float* ew2 = (const float*)d_in[5];
  const float* eb2 = (const float*)d_in[6];
  const float* fw0 = (const float*)d_in[7];
  const float* fb0 = (const float*)d_in[8];
  const float* fw1 = (const float*)d_in[9];
  const float* fb1 = (const float*)d_in[10];
  const float* fw2 = (const float*)d_in[11];
  const float* fb2 = (const float*)d_in[12];
  const float* fw3 = (const float*)d_in[13];
  const float* fb3 = (const float*)d_in[14];

  char* w = (char*)d_ws;
  __hip_bfloat16* DRb = (__hip_bfloat16*)(w);                 // 13107200 B
  __hip_bfloat16* H1b = (__hip_bfloat16*)(w + 13107200);      // 2097152 B
  __hip_bfloat16* H2b = (__hip_bfloat16*)(w + 15204352);
  __hip_bfloat16* H3b = (__hip_bfloat16*)(w + 17301504);
  __hip_bfloat16* W0T = (__hip_bfloat16*)(w + 19398656);      // 819200 B
  __hip_bfloat16* W1T = (__hip_bfloat16*)(w + 20217856);      // 131072 B
  __hip_bfloat16* W2T = (__hip_bfloat16*)(w + 20348928);      // 131072 B
  float* b0p = (float*)(w + 20480000);                        // 1024 B
  float* b1p = (float*)(w + 20481024);
  float* b2p = (float*)(w + 20482048);
  float* LUT = (float*)(w + 20483072);                        // 1048576 B
  float* Ei  = (float*)(w + 21531648);                        // 16384 B

  float* out = (float*)d_out;                                 // [0..7]=Etot, [8..]=Ei

  const int prep_elems = NPAD*DRLEN + 2*NPAD*NPAD + 3*NPAD;   // 541440
  prep_all<<<(prep_elems + 255)/256, 256, 0, stream>>>(
      fw0, fw1, fw2, fb0, fb1, fb2, W0T, W1T, W2T, b0p, b1p, b2p);

  lut_build_par<<<NLUT/EPB, 256, 0, stream>>>(ew0, eb0, ew1, eb1, ew2, eb2, LUT);
  embed_kernel<<<NPAIR, 128, 0, stream>>>(img, LUT, DRb);

  dim3 gg(NPAIR/64, NPAD/128);
  gemm_mfma<<<gg, 256, 0, stream>>>(DRb, W0T, b0p, H1b, DRLEN);
  gemm_mfma<<<gg, 256, 0, stream>>>(H1b, W1T, b1p, H2b, NPAD);
  gemm_mfma<<<gg, 256, 0, stream>>>(H2b, W2T, b2p, H3b, NPAD);

  gemv_out<<<NPAIR/4, 256, 0, stream>>>(H3b, fw3, fb3, Ei, out + 8);
  etot_k<<<B_, 256, 0, stream>>>(Ei, out);
}